// Round 2
// baseline (578.373 us; speedup 1.0000x reference)
//
#include <hip/hip_runtime.h>
#include <hip/hip_bf16.h>

using bf16x8 = __attribute__((ext_vector_type(8))) short;
using f32x4  = __attribute__((ext_vector_type(4))) float;

#define DEVI __device__ __forceinline__

// ---------------- gather: x[b][:] = E[inp[b]][:]  (fp32, 4KB/row) ----------------
__global__ __launch_bounds__(256) void k_gather(const float* __restrict__ E,
                                                const int* __restrict__ inp,
                                                float* __restrict__ x)
{
    const int b = blockIdx.x;
    const long r = inp[b];
    const f32x4* src = (const f32x4*)(E + r * 1024L);
    f32x4* dst = (f32x4*)(x + (long)b * 1024L);
    dst[threadIdx.x] = src[threadIdx.x];   // 256 threads x 16B = 4KB = one row
}

// ---------------- fp32x8 -> bf16x8 (RNE via __float2bfloat16) ----------------
DEVI bf16x8 cvt8(const f32x4 a, const f32x4 b)
{
    bf16x8 r;
#pragma unroll
    for (int j = 0; j < 4; ++j) {
        r[j]     = (short)__builtin_bit_cast(unsigned short, __float2bfloat16(a[j]));
        r[4 + j] = (short)__builtin_bit_cast(unsigned short, __float2bfloat16(b[j]));
    }
    return r;
}

// LDS tile: 128 rows x 64 bf16 (128B row). Granule = 8 bf16 = 16B; 8 granules/row.
// XOR swizzle: slot = kg ^ (row & 7)  (same involution on write and read).
DEVI bf16x8 lds_frag(const char* lds, int row, int kgl)
{
    const int s = kgl ^ (row & 7);
    return *(const bf16x8*)(lds + row * 128 + s * 16);
}

// ---------------- GEMM: C[M,N] = sum_p A_p[M,K_p] @ W_p[N,K_p]^T + bias (fp32 in/out,
// bf16 MFMA compute). MODE 0: gates (two pairs, bias = bx+bh). MODE 1: decoder (N-guard).
template <int MODE>
__global__ __launch_bounds__(256, 2) void k_gemm(
    const float* __restrict__ A1, const float* __restrict__ W1, int K1,
    const float* __restrict__ A2, const float* __restrict__ W2, int K2,
    const float* __restrict__ bias1, const float* __restrict__ bias2,
    float* __restrict__ C, long N, long ldc)
{
    __shared__ __align__(16) char sA[128 * 128];
    __shared__ __align__(16) char sB[128 * 128];
    const int t = threadIdx.x;
    const int l = t & 63;
    const int w = t >> 6;
    const int wr = w >> 1, wc = w & 1;             // 2x2 waves, 64x64 C each
    const long row0 = (long)blockIdx.y * 128;
    const long col0 = (long)blockIdx.x * 128;

    f32x4 acc[4][4] = {};

    const int npass = (MODE == 0) ? 2 : 1;
    for (int p = 0; p < npass; ++p) {
        const float* A = p ? A2 : A1;
        const float* W = p ? W2 : W1;
        const int K = p ? K2 : K1;
        for (int k0 = 0; k0 < K; k0 += 64) {
            // ---- issue all global loads for this K-tile (fp32, 32B/granule) ----
            f32x4 va[4][2], vb[4][2];
#pragma unroll
            for (int i = 0; i < 4; ++i) {
                const int g = i * 256 + t;         // granule 0..1023
                const int row = g >> 3, kg = g & 7;
                const float* pa = A + (row0 + row) * (long)K + k0 + kg * 8;
                va[i][0] = *(const f32x4*)pa;
                va[i][1] = *(const f32x4*)(pa + 4);
                long gr = col0 + row;
                if (MODE == 1) gr = (gr < N) ? gr : (N - 1);   // decoder N edge
                const float* pb = W + gr * (long)K + k0 + kg * 8;
                vb[i][0] = *(const f32x4*)pb;
                vb[i][1] = *(const f32x4*)(pb + 4);
            }
            __syncthreads();                       // WAR: prev compute done with LDS
            // ---- convert + swizzled LDS write ----
#pragma unroll
            for (int i = 0; i < 4; ++i) {
                const int g = i * 256 + t;
                const int row = g >> 3, kg = g & 7;
                const int slot = kg ^ (row & 7);
                *(bf16x8*)(sA + row * 128 + slot * 16) = cvt8(va[i][0], va[i][1]);
                *(bf16x8*)(sB + row * 128 + slot * 16) = cvt8(vb[i][0], vb[i][1]);
            }
            __syncthreads();                       // staged tile visible
            // ---- MFMA over the 64-deep K tile ----
#pragma unroll
            for (int ks = 0; ks < 2; ++ks) {
                bf16x8 af[4], bq[4];
#pragma unroll
                for (int m = 0; m < 4; ++m)
                    af[m] = lds_frag(sA, wr * 64 + m * 16 + (l & 15), ks * 4 + (l >> 4));
#pragma unroll
                for (int n = 0; n < 4; ++n)
                    bq[n] = lds_frag(sB, wc * 64 + n * 16 + (l & 15), ks * 4 + (l >> 4));
#pragma unroll
                for (int m = 0; m < 4; ++m)
#pragma unroll
                    for (int n = 0; n < 4; ++n)
                        acc[m][n] = __builtin_amdgcn_mfma_f32_16x16x32_bf16(
                            af[m], bq[n], acc[m][n], 0, 0, 0);
            }
        }
    }

    // epilogue: C/D layout col = lane&15, row = (lane>>4)*4 + reg  [m89/m91]
    const int lc = l & 15;
    const int r4 = (l >> 4) * 4;
#pragma unroll
    for (int n = 0; n < 4; ++n) {
        const long col = col0 + wc * 64 + n * 16 + lc;
        if (MODE == 1 && col >= N) continue;
        float bias = bias1[col];
        if (MODE == 0) bias += bias2[col];
#pragma unroll
        for (int m = 0; m < 4; ++m) {
            const long row = row0 + wr * 64 + m * 16 + r4;
#pragma unroll
            for (int r = 0; r < 4; ++r)
                C[(row + r) * ldc + col] = acc[m][n][r] + bias;
        }
    }
}

// ---------------- elementwise LSTM cell (fp32) ----------------
__global__ __launch_bounds__(256) void k_lstm(const float* __restrict__ gates,
                                              const float* __restrict__ c0,
                                              float* __restrict__ hx,
                                              float* __restrict__ cx)
{
    const int idx = blockIdx.x * 256 + threadIdx.x;   // 0 .. 512*2048-1
    const int b = idx >> 11;
    const int h = idx & 2047;
    const float* gb = gates + (long)b * 8192;
    float fg = gb[h];
    float ig = gb[2048 + h];
    float og = gb[4096 + h];
    float cg = gb[6144 + h];
    fg = 1.f / (1.f + __expf(-fg));
    ig = 1.f / (1.f + __expf(-ig));
    og = 1.f / (1.f + __expf(-og));
    cg = tanhf(cg);
    const float c = fg * c0[idx] + ig * cg;
    const float hv = og * tanhf(c);
    cx[idx] = c;
    hx[idx] = hv;
}

// ---------------- launch ----------------
extern "C" void kernel_launch(void* const* d_in, const int* in_sizes, int n_in,
                              void* d_out, int out_size, void* d_ws, size_t ws_size,
                              hipStream_t stream)
{
    const int*   inp = (const int*)d_in[0];
    const float* h0  = (const float*)d_in[1];
    const float* c0  = (const float*)d_in[2];
    const float* E   = (const float*)d_in[3];
    const float* Wx  = (const float*)d_in[4];   // (4,2048,1024) -> (8192,1024)
    const float* bx  = (const float*)d_in[5];   // (8192)
    const float* Wh  = (const float*)d_in[6];   // (8192,2048)
    const float* bh  = (const float*)d_in[7];
    const float* Wd  = (const float*)d_in[8];   // (50257,2048)
    const float* bd  = (const float*)d_in[9];

    float* out = (float*)d_out;                 // [512][50257]
    float* hx  = out + 512L * 50257L;           // [512][2048]
    float* cx  = hx + 512L * 2048L;             // [512][2048]

    // Scratch lives inside the `out` region (decoder GEMM overwrites it all later):
    // x: floats [0, 512*1024) = 2MB;  gates: floats [1M, 5M) = 16MB.  No d_ws use.
    float* x     = out;
    float* gates = out + (1L << 20);

    k_gather<<<512, 256, 0, stream>>>(E, inp, x);

    k_gemm<0><<<dim3(64, 4), 256, 0, stream>>>(
        x, Wx, 1024, h0, Wh, 2048, bx, bh, gates, 8192, 8192);

    k_lstm<<<4096, 256, 0, stream>>>(gates, c0, hx, cx);

    k_gemm<1><<<dim3(393, 4), 256, 0, stream>>>(
        hx, Wd, 2048, nullptr, nullptr, 0, bd, nullptr, out, 50257, 50257);
}

// Round 3
// 544.080 us; speedup vs baseline: 1.0630x; 1.0630x over previous
//
#include <hip/hip_runtime.h>
#include <hip/hip_bf16.h>

using bf16x8 = __attribute__((ext_vector_type(8))) short;
using f32x4  = __attribute__((ext_vector_type(4))) float;

#define DEVI __device__ __forceinline__

DEVI unsigned short bf16r(float f)
{
    return __builtin_bit_cast(unsigned short, __float2bfloat16(f));
}

// fp32x8 -> bf16x8 (RNE)
DEVI bf16x8 cvt8(const f32x4 a, const f32x4 b)
{
    bf16x8 r;
#pragma unroll
    for (int j = 0; j < 4; ++j) {
        r[j]     = (short)bf16r(a[j]);
        r[4 + j] = (short)bf16r(b[j]);
    }
    return r;
}

// ---------------- gather: x[b][:] = bf16(E[inp[b]][:]) ----------------
__global__ __launch_bounds__(256) void k_gather(const float* __restrict__ E,
                                                const int* __restrict__ inp,
                                                unsigned short* __restrict__ x)
{
    const int b = blockIdx.x;
    const long r = inp[b];
    const f32x4 v = ((const f32x4*)(E + r * 1024L))[threadIdx.x];
    ushort4 o;
    o.x = bf16r(v[0]); o.y = bf16r(v[1]); o.z = bf16r(v[2]); o.w = bf16r(v[3]);
    ((ushort4*)(x + (long)b * 1024L))[threadIdx.x] = o;
}

// ---------------- fp32 -> bf16 bulk convert (n multiple of 2048) ----------------
__global__ __launch_bounds__(256) void k_cvt(const float* __restrict__ in,
                                             unsigned short* __restrict__ out)
{
    const long i = (blockIdx.x * 256L + threadIdx.x) * 8;
    const f32x4 a = *(const f32x4*)(in + i);
    const f32x4 b = *(const f32x4*)(in + i + 4);
    *(bf16x8*)(out + i) = cvt8(a, b);
}

// ---------------- GEMM core: 128x128 tile, BK=64, 4 waves (2x2), bf16 MFMA ----------
// A: bf16 [M,K]; B: fp32 [N,K] (cvt to bf16 during LDS staging).
// LDS tile rows are 64 bf16 (128B); granule = 16B; XOR swizzle slot = j ^ (row&7).
struct Stage {
    bf16x8 a[4];      // 4 x 16B A granules
    f32x4  b[4][2];   // 4 x 32B B chunks
};

template <bool CLAMP>
DEVI void issue_loads(const unsigned short* __restrict__ A, long lda, long arow0,
                      const float* __restrict__ B, long ldb, long brow0, long bmax,
                      long k0, int t, Stage& s)
{
#pragma unroll
    for (int c = 0; c < 4; ++c) {
        const int ch = c * 256 + t;          // 0..1023
        const int r = ch >> 3, j = ch & 7;
        s.a[c] = *(const bf16x8*)(A + (arow0 + r) * lda + k0 + j * 8);
        long br = brow0 + r;
        if (CLAMP) br = (br < bmax) ? br : (bmax - 1);
        const float* pb = B + br * ldb + k0 + j * 8;
        s.b[c][0] = *(const f32x4*)pb;
        s.b[c][1] = *(const f32x4*)(pb + 4);
    }
}

DEVI void write_tile(char* sA, char* sB, int t, const Stage& s)
{
#pragma unroll
    for (int c = 0; c < 4; ++c) {
        const int ch = c * 256 + t;
        const int r = ch >> 3, j = ch & 7;
        const int off = r * 128 + ((j ^ (r & 7)) << 4);
        *(bf16x8*)(sA + off) = s.a[c];
        *(bf16x8*)(sB + off) = cvt8(s.b[c][0], s.b[c][1]);
    }
}

DEVI bf16x8 lds_frag(const char* lds, int row, int kgl)
{
    return *(const bf16x8*)(lds + row * 128 + ((kgl ^ (row & 7)) << 4));
}

DEVI void mfma_tile(const char* sA, const char* sB, int l, int wr, int wc,
                    f32x4 (&acc)[4][4])
{
#pragma unroll
    for (int ks = 0; ks < 2; ++ks) {
        bf16x8 af[4], bq[4];
#pragma unroll
        for (int m = 0; m < 4; ++m)
            af[m] = lds_frag(sA, wr * 64 + m * 16 + (l & 15), ks * 4 + (l >> 4));
#pragma unroll
        for (int n = 0; n < 4; ++n)
            bq[n] = lds_frag(sB, wc * 64 + n * 16 + (l & 15), ks * 4 + (l >> 4));
#pragma unroll
        for (int m = 0; m < 4; ++m)
#pragma unroll
            for (int n = 0; n < 4; ++n)
                acc[m][n] = __builtin_amdgcn_mfma_f32_16x16x32_bf16(
                    af[m], bq[n], acc[m][n], 0, 0, 0);
    }
}

template <bool CLAMP>
DEVI void gemm_core(const unsigned short* __restrict__ A, long lda, long arow0,
                    const float* __restrict__ B, long ldb, long brow0, long bmax,
                    int K, long kbase, int t, int l, int wr, int wc,
                    char* sA, char* sB, f32x4 (&acc)[4][4])
{
    Stage s0, s1;
    const int nt = K >> 6;   // K/64, even for all call sites (16 or 32)
    issue_loads<CLAMP>(A, lda, arow0, B, ldb, brow0, bmax, kbase, t, s0);
    for (int ti = 0; ti < nt; ti += 2) {
        __syncthreads();                     // prev tile fully consumed
        write_tile(sA, sB, t, s0);           // waits vmcnt on s0 loads
        __syncthreads();
        issue_loads<CLAMP>(A, lda, arow0, B, ldb, brow0, bmax,
                           kbase + (ti + 1) * 64, t, s1);   // flies during MFMA
        mfma_tile(sA, sB, l, wr, wc, acc);
        __syncthreads();
        write_tile(sA, sB, t, s1);
        __syncthreads();
        if (ti + 2 < nt)
            issue_loads<CLAMP>(A, lda, arow0, B, ldb, brow0, bmax,
                               kbase + (ti + 2) * 64, t, s0);
        mfma_tile(sA, sB, l, wr, wc, acc);
    }
}

// ---------------- gates GEMM: partial chunk z of (x@Wx^T | h0@Wh^T) ----------------
// grid (4 rowtiles, 64 coltiles, 3 chunks); partials summed (with biases) in k_lstm.
__global__ __launch_bounds__(256, 2) void k_gates(
    const unsigned short* __restrict__ xb, const float* __restrict__ Wx,
    const unsigned short* __restrict__ h0b, const float* __restrict__ Wh,
    float* __restrict__ g0, float* __restrict__ g1, float* __restrict__ g2)
{
    __shared__ __align__(16) char sA[128 * 128];
    __shared__ __align__(16) char sB[128 * 128];
    const int t = threadIdx.x, l = t & 63, w = t >> 6;
    const int wr = w >> 1, wc = w & 1;
    const long row0 = (long)blockIdx.x * 128;
    const long col0 = (long)blockIdx.y * 128;
    const int z = blockIdx.z;

    const unsigned short* A; const float* B; long lda, ldb, kbase; float* C;
    if (z == 0)      { A = xb;  lda = 1024; B = Wx; ldb = 1024; kbase = 0;    C = g0; }
    else if (z == 1) { A = h0b; lda = 2048; B = Wh; ldb = 2048; kbase = 0;    C = g1; }
    else             { A = h0b; lda = 2048; B = Wh; ldb = 2048; kbase = 1024; C = g2; }

    f32x4 acc[4][4] = {};
    gemm_core<false>(A, lda, row0, B, ldb, col0, 1L << 40, 1024, kbase,
                     t, l, wr, wc, sA, sB, acc);

    const int lc = l & 15, r4 = (l >> 4) * 4;
#pragma unroll
    for (int n = 0; n < 4; ++n) {
        const long col = col0 + wc * 64 + n * 16 + lc;
#pragma unroll
        for (int m = 0; m < 4; ++m) {
            const long row = row0 + wr * 64 + m * 16 + r4;
#pragma unroll
            for (int r = 0; r < 4; ++r)
                C[(row + r) * 8192 + col] = acc[m][n][r];
        }
    }
}

// ---------------- decoder GEMM: out = hx @ Wd^T + bd ----------------
__global__ __launch_bounds__(256, 2) void k_dec(
    const unsigned short* __restrict__ hxb, const float* __restrict__ Wd,
    const float* __restrict__ bd, float* __restrict__ out)
{
    __shared__ __align__(16) char sA[128 * 128];
    __shared__ __align__(16) char sB[128 * 128];
    const int t = threadIdx.x, l = t & 63, w = t >> 6;
    const int wr = w >> 1, wc = w & 1;
    const long row0 = (long)blockIdx.x * 128;
    const long col0 = (long)blockIdx.y * 128;
    const long N = 50257;

    f32x4 acc[4][4] = {};
    gemm_core<true>(hxb, 2048, row0, Wd, 2048, col0, N, 2048, 0,
                    t, l, wr, wc, sA, sB, acc);

    const int lc = l & 15, r4 = (l >> 4) * 4;
#pragma unroll
    for (int n = 0; n < 4; ++n) {
        const long col = col0 + wc * 64 + n * 16 + lc;
        if (col >= N) continue;
        const float bias = bd[col];
#pragma unroll
        for (int m = 0; m < 4; ++m) {
            const long row = row0 + wr * 64 + m * 16 + r4;
#pragma unroll
            for (int r = 0; r < 4; ++r)
                out[(row + r) * N + col] = acc[m][n][r] + bias;
        }
    }
}

// ---------------- elementwise LSTM cell: combine 3 partials + biases ----------------
__global__ __launch_bounds__(256) void k_lstm(
    const float* __restrict__ g0, const float* __restrict__ g1,
    const float* __restrict__ g2, const float* __restrict__ bx,
    const float* __restrict__ bh, const float* __restrict__ c0,
    float* __restrict__ hx, float* __restrict__ cx,
    unsigned short* __restrict__ hxb)
{
    const int i = blockIdx.x * 256 + threadIdx.x;   // 0 .. 512*2048/4-1
    const int b = i >> 9;
    const int hc = (i & 511) << 2;
    const long base = (long)b * 8192;

    f32x4 g[4];
#pragma unroll
    for (int gi = 0; gi < 4; ++gi) {
        const long off = base + gi * 2048 + hc;
        const int boff = gi * 2048 + hc;
        g[gi] = *(const f32x4*)(g0 + off);
        g[gi] += *(const f32x4*)(g1 + off);
        g[gi] += *(const f32x4*)(g2 + off);
        g[gi] += *(const f32x4*)(bx + boff);
        g[gi] += *(const f32x4*)(bh + boff);
    }
    const f32x4 c0v = *(const f32x4*)(c0 + (long)b * 2048 + hc);

    f32x4 cv, hv;
    ushort4 hb;
#pragma unroll
    for (int j = 0; j < 4; ++j) {
        const float fg = 1.f / (1.f + __expf(-g[0][j]));
        const float ig = 1.f / (1.f + __expf(-g[1][j]));
        const float og = 1.f / (1.f + __expf(-g[2][j]));
        const float e2 = __expf(2.f * g[3][j]);
        const float ct = 1.f - 2.f / (e2 + 1.f);          // tanh, overflow-safe
        const float c  = fg * c0v[j] + ig * ct;
        const float e2c = __expf(2.f * c);
        const float th  = 1.f - 2.f / (e2c + 1.f);
        cv[j] = c;
        hv[j] = og * th;
    }
    hb.x = bf16r(hv[0]); hb.y = bf16r(hv[1]); hb.z = bf16r(hv[2]); hb.w = bf16r(hv[3]);

    const long o = (long)b * 2048 + hc;
    *(f32x4*)(cx + o) = cv;
    *(f32x4*)(hx + o) = hv;
    *(ushort4*)(hxb + o) = hb;
}

// ---------------- launch ----------------
extern "C" void kernel_launch(void* const* d_in, const int* in_sizes, int n_in,
                              void* d_out, int out_size, void* d_ws, size_t ws_size,
                              hipStream_t stream)
{
    const int*   inp = (const int*)d_in[0];
    const float* h0  = (const float*)d_in[1];
    const float* c0  = (const float*)d_in[2];
    const float* E   = (const float*)d_in[3];
    const float* Wx  = (const float*)d_in[4];   // (8192,1024)
    const float* bx  = (const float*)d_in[5];
    const float* Wh  = (const float*)d_in[6];   // (8192,2048)
    const float* bh  = (const float*)d_in[7];
    const float* Wd  = (const float*)d_in[8];   // (50257,2048)
    const float* bd  = (const float*)d_in[9];

    float* out = (float*)d_out;                 // [512][50257]
    float* hx  = out + 512L * 50257L;           // [512][2048]
    float* cx  = hx + 512L * 2048L;

    // Scratch in the out region — all consumed before k_dec overwrites out:
    //   xb  @ 0        (512x1024 bf16 = 0.25M floats)
    //   g0  @ 1M, g1 @ 5M, g2 @ 9M   (each 4M floats)
    //   h0b @ 13M      (512x2048 bf16 = 0.5M floats)
    unsigned short* xb  = (unsigned short*)out;
    float* g0 = out + (1L << 20);
    float* g1 = out + (5L << 20);
    float* g2 = out + (9L << 20);
    unsigned short* h0b = (unsigned short*)(out + (13L << 20));
    // hxb is read DURING k_dec (which writes all of out) -> must live in d_ws (2 MB).
    unsigned short* hxb = (unsigned short*)d_ws;

    k_gather<<<512, 256, 0, stream>>>(E, inp, xb);
    k_cvt<<<512, 256, 0, stream>>>(h0, h0b);    // 1,048,576 elems

    k_gates<<<dim3(4, 64, 3), 256, 0, stream>>>(xb, Wx, h0b, Wh, g0, g1, g2);

    k_lstm<<<1024, 256, 0, stream>>>(g0, g1, g2, bx, bh, c0, hx, cx, hxb);

    k_dec<<<dim3(4, 393), 256, 0, stream>>>(hxb, Wd, bd, out);
}

// Round 5
// 282.847 us; speedup vs baseline: 2.0448x; 1.9236x over previous
//
#include <hip/hip_runtime.h>
#include <hip/hip_bf16.h>

using bf16x8 = __attribute__((ext_vector_type(8))) short;
using f32x4  = __attribute__((ext_vector_type(4))) float;

#define DEVI __device__ __forceinline__

DEVI unsigned short bf16r(float f)
{
    return __builtin_bit_cast(unsigned short, __float2bfloat16(f));
}

DEVI bf16x8 cvt8(const f32x4 a, const f32x4 b)
{
    bf16x8 r;
#pragma unroll
    for (int j = 0; j < 4; ++j) {
        r[j]     = (short)bf16r(a[j]);
        r[4 + j] = (short)bf16r(b[j]);
    }
    return r;
}

// ---------------- gather: x[b][:] = bf16(E[inp[b]][:]) ----------------
__global__ __launch_bounds__(256) void k_gather(const float* __restrict__ E,
                                                const int* __restrict__ inp,
                                                unsigned short* __restrict__ x)
{
    const int b = blockIdx.x;
    const long r = inp[b];
    const f32x4 v = ((const f32x4*)(E + r * 1024L))[threadIdx.x];
    ushort4 o;
    o.x = bf16r(v[0]); o.y = bf16r(v[1]); o.z = bf16r(v[2]); o.w = bf16r(v[3]);
    ((ushort4*)(x + (long)b * 1024L))[threadIdx.x] = o;
}

// ---------------- fp32 -> bf16 bulk convert ----------------
__global__ __launch_bounds__(256) void k_cvt(const float* __restrict__ in,
                                             unsigned short* __restrict__ out)
{
    const long i = (blockIdx.x * 256L + threadIdx.x) * 8;
    const f32x4 a = *(const f32x4*)(in + i);
    const f32x4 b = *(const f32x4*)(in + i + 4);
    *(bf16x8*)(out + i) = cvt8(a, b);
}

// =====================================================================
// GEMM core (m97 structure): 128x128 tile, BK=64, 4 waves (2x2).
//   A: bf16 [M,K] -> LDS 128x64bf16 (16KB), granule 16B, swizzle j^(row&7)
//   B: fp32 [N,K] -> LDS 128x64f32 (32KB), granule 16B, swizzle s^rx(row),
//      rx(row) = ((row&7)<<1)|((row>>3)&1)  (bijective on 16 rows)
// global_load_lds width 16, LINEAR LDS dest, swizzle pre-applied to the
// GLOBAL source address; read side applies the same XOR (rule #21).
// Fragments: B converted fp32->bf16 at read time (cvt8).
// =====================================================================

DEVI void mfma_tile(const char* sA, const char* sB, int l, int wr, int wc,
                    f32x4 (&acc)[4][4])
{
#pragma unroll
    for (int ks = 0; ks < 2; ++ks) {
        bf16x8 af[4], bq[4];
#pragma unroll
        for (int m = 0; m < 4; ++m) {
            const int ar = wr * 64 + m * 16 + (l & 15);
            const int j  = ks * 4 + (l >> 4);
            af[m] = *(const bf16x8*)(sA + ar * 128 + ((j ^ (ar & 7)) << 4));
        }
#pragma unroll
        for (int n = 0; n < 4; ++n) {
            const int br = wc * 64 + n * 16 + (l & 15);
            const int rx = ((br & 7) << 1) | ((br >> 3) & 1);
            const int f  = ks * 4 + (l >> 4);
            const f32x4 lo = *(const f32x4*)(sB + br * 256 + (((2 * f)     ^ rx) << 4));
            const f32x4 hi = *(const f32x4*)(sB + br * 256 + (((2 * f + 1) ^ rx) << 4));
            bq[n] = cvt8(lo, hi);
        }
#pragma unroll
        for (int m = 0; m < 4; ++m)
#pragma unroll
            for (int n = 0; n < 4; ++n)
                acc[m][n] = __builtin_amdgcn_mfma_f32_16x16x32_bf16(
                    af[m], bq[n], acc[m][n], 0, 0, 0);
    }
}

template <bool CLAMP>
DEVI void gemm_core(const unsigned short* __restrict__ A, long lda, long arow0,
                    const float* __restrict__ B, long ldb, long brow0, long bmax,
                    int ntiles, long kbase, int t, char* sA, char* sB,
                    f32x4 (&acc)[4][4])
{
    const int l = t & 63;
    const int wr = (t >> 7) & 1, wc = (t >> 6) & 1;

    // Per-thread source pointers (swizzle folded in), advanced by 64 elems/tile.
    const unsigned short* ap[4];
    const float* bp[8];
#pragma unroll
    for (int i = 0; i < 4; ++i) {
        const int g = i * 256 + t, row = g >> 3, js = g & 7;
        ap[i] = A + (arow0 + row) * lda + kbase + (long)((js ^ (row & 7)) * 8);
    }
#pragma unroll
    for (int i = 0; i < 8; ++i) {
        const int g = i * 256 + t, row = g >> 4, sx = g & 15;
        const int rx = ((row & 7) << 1) | ((row >> 3) & 1);
        long br = brow0 + row;
        if (CLAMP) br = (br < bmax) ? br : (bmax - 1);
        bp[i] = B + br * ldb + kbase + (long)((sx ^ rx) * 4);
    }

    for (int ti = 0; ti < ntiles; ++ti) {
        __syncthreads();                       // all waves done reading prev tile
#pragma unroll
        for (int i = 0; i < 4; ++i)
            __builtin_amdgcn_global_load_lds(
                (const __attribute__((address_space(1))) void*)(ap[i]),
                (__attribute__((address_space(3))) void*)(sA + (i * 256 + t) * 16),
                16, 0, 0);
#pragma unroll
        for (int i = 0; i < 8; ++i)
            __builtin_amdgcn_global_load_lds(
                (const __attribute__((address_space(1))) void*)(bp[i]),
                (__attribute__((address_space(3))) void*)(sB + (i * 256 + t) * 16),
                16, 0, 0);
        __syncthreads();                       // vmcnt drained before barrier -> tile visible
#pragma unroll
        for (int i = 0; i < 4; ++i) ap[i] += 64;
#pragma unroll
        for (int i = 0; i < 8; ++i) bp[i] += 64;
        mfma_tile(sA, sB, l, wr, wc, acc);
    }
}

// ---------------- gates GEMM: chunk z of (x@Wx^T | h0@Wh^T) ----------------
// 768 blocks: XCD-chunked swizzle (q=96,r=0); L -> (mtile, ntile, z),
// 4 consecutive L = 4 row-tiles of one weight strip on the SAME XCD.
__global__ __launch_bounds__(256, 3) void k_gates(
    const unsigned short* __restrict__ xb, const float* __restrict__ Wx,
    const unsigned short* __restrict__ h0b, const float* __restrict__ Wh,
    float* __restrict__ g0, float* __restrict__ g1, float* __restrict__ g2)
{
    __shared__ __align__(16) char sA[128 * 128];
    __shared__ __align__(16) char sB[128 * 256];
    const int t = threadIdx.x;
    const int bid = blockIdx.x;
    const int xcd = bid & 7, slot = bid >> 3;
    const int L = xcd * 96 + slot;
    const int mtile = L & 3;
    const int rest = L >> 2;
    const int ntile = rest & 63;
    const int z = rest >> 6;

    const unsigned short* A; const float* B; long lda, ldb, kbase; float* C;
    if (z == 0)      { A = xb;  lda = 1024; B = Wx; ldb = 1024; kbase = 0;    C = g0; }
    else if (z == 1) { A = h0b; lda = 2048; B = Wh; ldb = 2048; kbase = 0;    C = g1; }
    else             { A = h0b; lda = 2048; B = Wh; ldb = 2048; kbase = 1024; C = g2; }

    f32x4 acc[4][4] = {};
    gemm_core<false>(A, lda, (long)mtile * 128, B, ldb, (long)ntile * 128,
                     1L << 40, 16, kbase, t, sA, sB, acc);

    const int l = t & 63;
    const int wr = (t >> 7) & 1, wc = (t >> 6) & 1;
    const int lc = l & 15, r4 = (l >> 4) * 4;
#pragma unroll
    for (int n = 0; n < 4; ++n) {
        const long col = (long)ntile * 128 + wc * 64 + n * 16 + lc;
#pragma unroll
        for (int m = 0; m < 4; ++m) {
            const long row = (long)mtile * 128 + wr * 64 + m * 16 + r4;
#pragma unroll
            for (int r = 0; r < 4; ++r)
                C[(row + r) * 8192 + col] = acc[m][n][r];
        }
    }
}

// ---------------- decoder GEMM: out = hx @ Wd^T + bd ----------------
// 1572 blocks: bijective XCD-chunk swizzle (q=196, r=4, m204 formula).
__global__ __launch_bounds__(256, 3) void k_dec(
    const unsigned short* __restrict__ hxb, const float* __restrict__ Wd,
    const float* __restrict__ bd, float* __restrict__ out)
{
    __shared__ __align__(16) char sA[128 * 128];
    __shared__ __align__(16) char sB[128 * 256];
    const int t = threadIdx.x;
    const int bid = blockIdx.x;
    const int xcd = bid & 7, slot = bid >> 3;
    const int L = xcd * 196 + (xcd < 4 ? xcd : 4) + slot;
    const int mtile = L & 3;
    const int ntile = L >> 2;                  // 0..392
    const long N = 50257;

    f32x4 acc[4][4] = {};
    gemm_core<true>(hxb, 2048, (long)mtile * 128, Wd, 2048, (long)ntile * 128,
                    N, 32, 0, t, sA, sB, acc);

    const int l = t & 63;
    const int wr = (t >> 7) & 1, wc = (t >> 6) & 1;
    const int lc = l & 15, r4 = (l >> 4) * 4;
#pragma unroll
    for (int n = 0; n < 4; ++n) {
        const long col = (long)ntile * 128 + wc * 64 + n * 16 + lc;
        if (col >= N) continue;
        const float bias = bd[col];
#pragma unroll
        for (int m = 0; m < 4; ++m) {
            const long row = (long)mtile * 128 + wr * 64 + m * 16 + r4;
#pragma unroll
            for (int r = 0; r < 4; ++r)
                out[(row + r) * N + col] = acc[m][n][r] + bias;
        }
    }
}

// ---------------- elementwise LSTM cell: combine 3 partials + biases ----------------
__global__ __launch_bounds__(256) void k_lstm(
    const float* __restrict__ g0, const float* __restrict__ g1,
    const float* __restrict__ g2, const float* __restrict__ bx,
    const float* __restrict__ bh, const float* __restrict__ c0,
    float* __restrict__ hx, float* __restrict__ cx,
    unsigned short* __restrict__ hxb)
{
    const int i = blockIdx.x * 256 + threadIdx.x;
    const int b = i >> 9;
    const int hc = (i & 511) << 2;
    const long base = (long)b * 8192;

    f32x4 g[4];
#pragma unroll
    for (int gi = 0; gi < 4; ++gi) {
        const long off = base + gi * 2048 + hc;
        const int boff = gi * 2048 + hc;
        g[gi] = *(const f32x4*)(g0 + off);
        g[gi] += *(const f32x4*)(g1 + off);
        g[gi] += *(const f32x4*)(g2 + off);
        g[gi] += *(const f32x4*)(bx + boff);
        g[gi] += *(const f32x4*)(bh + boff);
    }
    const f32x4 c0v = *(const f32x4*)(c0 + (long)b * 2048 + hc);

    f32x4 cv, hv;
    ushort4 hb;
#pragma unroll
    for (int j = 0; j < 4; ++j) {
        const float fg = 1.f / (1.f + __expf(-g[0][j]));
        const float ig = 1.f / (1.f + __expf(-g[1][j]));
        const float og = 1.f / (1.f + __expf(-g[2][j]));
        const float e2 = __expf(2.f * g[3][j]);
        const float ct = 1.f - 2.f / (e2 + 1.f);
        const float c  = fg * c0v[j] + ig * ct;
        const float e2c = __expf(2.f * c);
        const float th  = 1.f - 2.f / (e2c + 1.f);
        cv[j] = c;
        hv[j] = og * th;
    }
    hb.x = bf16r(hv[0]); hb.y = bf16r(hv[1]); hb.z = bf16r(hv[2]); hb.w = bf16r(hv[3]);

    const long o = (long)b * 2048 + hc;
    *(f32x4*)(cx + o) = cv;
    *(f32x4*)(hx + o) = hv;
    *(ushort4*)(hxb + o) = hb;
}

// ---------------- launch ----------------
extern "C" void kernel_launch(void* const* d_in, const int* in_sizes, int n_in,
                              void* d_out, int out_size, void* d_ws, size_t ws_size,
                              hipStream_t stream)
{
    const int*   inp = (const int*)d_in[0];
    const float* h0  = (const float*)d_in[1];
    const float* c0  = (const float*)d_in[2];
    const float* E   = (const float*)d_in[3];
    const float* Wx  = (const float*)d_in[4];   // (8192,1024)
    const float* bx  = (const float*)d_in[5];
    const float* Wh  = (const float*)d_in[6];   // (8192,2048)
    const float* bh  = (const float*)d_in[7];
    const float* Wd  = (const float*)d_in[8];   // (50257,2048)
    const float* bd  = (const float*)d_in[9];

    float* out = (float*)d_out;                 // [512][50257]
    float* hx  = out + 512L * 50257L;           // [512][2048]
    float* cx  = hx + 512L * 2048L;

    // Scratch in the out region — all consumed before k_dec overwrites out:
    //   xb @ 0 (0.5MB), g0 @ 1M floats, g1 @ 5M, g2 @ 9M, h0b @ 13M floats.
    unsigned short* xb  = (unsigned short*)out;
    float* g0 = out + (1L << 20);
    float* g1 = out + (5L << 20);
    float* g2 = out + (9L << 20);
    unsigned short* h0b = (unsigned short*)(out + (13L << 20));
    // hxb read during k_dec (which writes out) -> lives in d_ws (2 MB).
    unsigned short* hxb = (unsigned short*)d_ws;

    k_gather<<<512, 256, 0, stream>>>(E, inp, xb);
    k_cvt<<<512, 256, 0, stream>>>(h0, h0b);

    k_gates<<<768, 256, 0, stream>>>(xb, Wx, h0b, Wh, g0, g1, g2);

    k_lstm<<<1024, 256, 0, stream>>>(g0, g1, g2, bx, bh, c0, hx, cx, hxb);

    k_dec<<<1572, 256, 0, stream>>>(hxb, Wd, bd, out);
}